// Round 6
// baseline (427.367 us; speedup 1.0000x reference)
//
#include <hip/hip_runtime.h>

typedef __bf16 bf16;
typedef __bf16 bf16x8 __attribute__((ext_vector_type(8)));
typedef __bf16 bf16x4 __attribute__((ext_vector_type(4)));
typedef float f32x4 __attribute__((ext_vector_type(4)));
typedef float f32x16 __attribute__((ext_vector_type(16)));
typedef unsigned u32x4 __attribute__((ext_vector_type(4)));

#define EXP2F(x) __builtin_amdgcn_exp2f(x)

#define LOAD_LDS16(gp, lp)                                                     \
  __builtin_amdgcn_global_load_lds(                                            \
      (const __attribute__((address_space(1))) void*)(gp),                     \
      (__attribute__((address_space(3))) void*)(lp), 16, 0, 0)

// ---------------- f32 -> bf16 convert (x) ----------------
__global__ __launch_bounds__(256) void k_cvt_x(const float* __restrict__ in,
                                               bf16* __restrict__ out, int n4) {
  int i = blockIdx.x * 256 + threadIdx.x;
  if (i < n4) {
    float4 v = ((const float4*)in)[i];
    bf16x4 o = {(bf16)v.x, (bf16)v.y, (bf16)v.z, (bf16)v.w};
    ((bf16x4*)out)[i] = o;
  }
}

// ---------------- f32 [R][C] -> bf16 [C][R] transpose ----------------
__global__ __launch_bounds__(256) void k_transpose(const float* __restrict__ in,
                                                   bf16* __restrict__ out,
                                                   int R, int C) {
  __shared__ bf16 t[64 * 65];
  int tid = threadIdx.x;
  int c0 = blockIdx.x * 64, r0 = blockIdx.y * 64;
#pragma unroll
  for (int i = 0; i < 16; ++i) {
    int f = i * 256 + tid;
    int rl = f >> 6, cl = f & 63;
    t[rl * 65 + cl] = (bf16)in[(size_t)(r0 + rl) * C + c0 + cl];
  }
  __syncthreads();
#pragma unroll
  for (int i = 0; i < 16; ++i) {
    int f = i * 256 + tid;
    int cl = f >> 6, rl = f & 63;
    out[(size_t)(c0 + cl) * R + r0 + rl] = t[rl * 65 + cl];
  }
}

// ---- bf16 GEMM, BMx256 tile, 8-phase counted-vmcnt schedule (T3+T4+T5) ----
// C[M][N] = A[M][K] * Bt[N][K]^T. 512 thr = 8 waves (2M x 4N).
// BM=256: wave=128x64, 4 sub-phases/K-tile (validated round-5 schedule).
// BM=128: wave=64x64, 2 sub-phases/K-tile, vmcnt(3) pipeline (same FIFO rule:
//   certification of tile-T data happens one phase before its ds_read).
template <typename OutT, int BM>
__global__ __launch_bounds__(512, 2) void k_gemm256(const bf16* __restrict__ A,
                                                    const bf16* __restrict__ Bt,
                                                    OutT* __restrict__ C,
                                                    int M, int N, int K) {
  constexpr int ASZ = 4 * BM * 8;   // elems per kh buffer
  constexpr int MREP = BM / 32;     // per-wave 16-row tiles (8 or 4)
  __shared__ alignas(16) bf16 As[2][2][ASZ];
  __shared__ alignas(16) bf16 Bs[2][2][4 * 256 * 8];
  int tid = threadIdx.x;
  int wid = tid >> 6, lane = tid & 63;
  int g = lane >> 4, lr = lane & 15;
  int wrow = (wid >> 2) * (BM / 2), wcol = (wid & 3) * 64;
  int row0 = blockIdx.x * BM, col0 = blockIdx.y * 256;
  int NT = K >> 6;
  f32x4 acc[MREP][4] = {};

  auto stageA = [&](int buf, int kh, int kt) {
#pragma unroll
    for (int pass = 0; pass < BM / 128; ++pass) {
      int slot = pass * 512 + tid;
      int kseg, row;
      if constexpr (BM == 256) { kseg = slot >> 8; row = slot & 255; }
      else { kseg = slot >> 7; row = slot & 127; }
      LOAD_LDS16(A + (size_t)(row0 + row) * K + kt * 64 + kh * 32 + kseg * 8,
                 &As[buf][kh][slot * 8]);
    }
  };
  auto stageB = [&](int buf, int kh, int kt) {
#pragma unroll
    for (int pass = 0; pass < 2; ++pass) {
      int slot = pass * 512 + tid;
      int kseg = slot >> 8, row = slot & 255;
      LOAD_LDS16(Bt + (size_t)(col0 + row) * K + kt * 64 + kh * 32 + kseg * 8,
                 &Bs[buf][kh][slot * 8]);
    }
  };
  auto dsA = [&](int buf, int s, int mq, bf16x8* af) {
#pragma unroll
    for (int i = 0; i < 4; ++i)
      af[i] = *(const bf16x8*)&As[buf][s]
                  [(g * BM + wrow + (mq * 4 + i) * 16 + lr) * 8];
  };
  auto dsB = [&](int buf, int s, bf16x8* bfr) {
#pragma unroll
    for (int i = 0; i < 4; ++i)
      bfr[i] = *(const bf16x8*)&Bs[buf][s][((g << 8) + wcol + i * 16 + lr) * 8];
  };
  auto mfma16 = [&](int mq, bf16x8* af, bf16x8* bfr) {
    __builtin_amdgcn_s_setprio(1);
#pragma unroll
    for (int i = 0; i < 4; ++i)
#pragma unroll
      for (int n = 0; n < 4; ++n)
        acc[mq * 4 + i][n] = __builtin_amdgcn_mfma_f32_16x16x32_bf16(
            af[i], bfr[n], acc[mq * 4 + i][n], 0, 0, 0);
    __builtin_amdgcn_s_setprio(0);
  };

  // prologue: tile 0 fully; certify kh0(0)
  stageA(0, 0, 0);
  stageB(0, 0, 0);
  stageA(0, 1, 0);
  stageB(0, 1, 0);
  if constexpr (BM == 256)
    asm volatile("s_waitcnt vmcnt(4)" ::: "memory");
  else
    asm volatile("s_waitcnt vmcnt(3)" ::: "memory");
  __builtin_amdgcn_s_barrier();

  for (int T = 0; T < NT; ++T) {
    int buf = T & 1, nbuf = buf ^ 1;
    bool more = (T + 1 < NT);
    bf16x8 af[4], bfr[4];
    if constexpr (BM == 256) {
      // ---- p0: kh0, mq0 ----
      dsA(buf, 0, 0, af);
      dsB(buf, 0, bfr);
      if (more) stageA(nbuf, 0, T + 1);
      __builtin_amdgcn_sched_barrier(0);
      __builtin_amdgcn_s_barrier();
      asm volatile("s_waitcnt lgkmcnt(0)" ::: "memory");
      __builtin_amdgcn_sched_barrier(0);
      mfma16(0, af, bfr);
      __builtin_amdgcn_s_barrier();
      // ---- p1: kh0, mq1 ----
      dsA(buf, 0, 1, af);
      if (more) {
        stageB(nbuf, 0, T + 1);
        asm volatile("s_waitcnt vmcnt(4)" ::: "memory");  // kh1(T) landed
      } else {
        asm volatile("s_waitcnt vmcnt(0)" ::: "memory");
      }
      __builtin_amdgcn_sched_barrier(0);
      __builtin_amdgcn_s_barrier();
      asm volatile("s_waitcnt lgkmcnt(0)" ::: "memory");
      __builtin_amdgcn_sched_barrier(0);
      mfma16(1, af, bfr);
      __builtin_amdgcn_s_barrier();
      // ---- p2: kh1, mq0 ----
      dsA(buf, 1, 0, af);
      dsB(buf, 1, bfr);
      if (more) stageA(nbuf, 1, T + 1);
      __builtin_amdgcn_sched_barrier(0);
      __builtin_amdgcn_s_barrier();
      asm volatile("s_waitcnt lgkmcnt(0)" ::: "memory");
      __builtin_amdgcn_sched_barrier(0);
      mfma16(0, af, bfr);
      __builtin_amdgcn_s_barrier();
      // ---- p3: kh1, mq1 ----
      dsA(buf, 1, 1, af);
      if (more) {
        stageB(nbuf, 1, T + 1);
        asm volatile("s_waitcnt vmcnt(4)" ::: "memory");  // kh0(T+1) landed
      }
      __builtin_amdgcn_sched_barrier(0);
      __builtin_amdgcn_s_barrier();
      asm volatile("s_waitcnt lgkmcnt(0)" ::: "memory");
      __builtin_amdgcn_sched_barrier(0);
      mfma16(1, af, bfr);
      __builtin_amdgcn_s_barrier();
    } else {
      // ---- p0: kh0 ----
      dsA(buf, 0, 0, af);
      dsB(buf, 0, bfr);
      if (more) {
        stageA(nbuf, 0, T + 1);
        stageB(nbuf, 0, T + 1);
        asm volatile("s_waitcnt vmcnt(3)" ::: "memory");  // kh1(T) landed
      } else {
        asm volatile("s_waitcnt vmcnt(0)" ::: "memory");
      }
      __builtin_amdgcn_sched_barrier(0);
      __builtin_amdgcn_s_barrier();
      asm volatile("s_waitcnt lgkmcnt(0)" ::: "memory");
      __builtin_amdgcn_sched_barrier(0);
      mfma16(0, af, bfr);
      __builtin_amdgcn_s_barrier();
      // ---- p1: kh1 ----
      dsA(buf, 1, 0, af);
      dsB(buf, 1, bfr);
      if (more) {
        stageA(nbuf, 1, T + 1);
        stageB(nbuf, 1, T + 1);
        asm volatile("s_waitcnt vmcnt(3)" ::: "memory");  // kh0(T+1) landed
      }
      __builtin_amdgcn_sched_barrier(0);
      __builtin_amdgcn_s_barrier();
      asm volatile("s_waitcnt lgkmcnt(0)" ::: "memory");
      __builtin_amdgcn_sched_barrier(0);
      mfma16(0, af, bfr);
      __builtin_amdgcn_s_barrier();
    }
  }

#pragma unroll
  for (int mi = 0; mi < MREP; ++mi)
#pragma unroll
    for (int ni = 0; ni < 4; ++ni) {
      int rb = row0 + wrow + mi * 16 + g * 4;
      int cc = col0 + wcol + ni * 16 + lr;
#pragma unroll
      for (int r = 0; r < 4; ++r) {
        float v = acc[mi][ni][r];
        C[(size_t)(rb + r) * N + cc] = (OutT)v;
      }
    }
}

// ---------------- QK RMS-norm (in place on bf16 qkv) ----------------
// Q gets 1/sqrt(128) * log2(e) folded in (softmax done in exp2 domain).
__global__ __launch_bounds__(256) void k_qknorm(bf16* __restrict__ qkv,
                                                const float* __restrict__ qs,
                                                const float* __restrict__ ks) {
  int tok = blockIdx.x;
  int wid = threadIdx.x >> 6, lane = threadIdx.x & 63;
  int d = lane * 2;
  bf16* rowp = qkv + (size_t)tok * 3072;
#pragma unroll
  for (int i = 0; i < 5; ++i) {
    int cb = (i < 4) ? (wid + i * 4) * 128 : 2048 + wid * 128;
    float v0 = (float)rowp[cb + d], v1 = (float)rowp[cb + d + 1];
    float ss = v0 * v0 + v1 * v1;
#pragma unroll
    for (int off = 1; off < 64; off <<= 1) ss += __shfl_xor(ss, off);
    float r = rsqrtf(ss * (1.0f / 128.0f) + 1e-6f);
    float s0, s1, extra;
    if (i < 4) {
      s0 = qs[d]; s1 = qs[d + 1];
      extra = 0.08838834764831845f * 1.4426950408889634f;  // rsqrt(d)*log2(e)
    } else {
      s0 = ks[d]; s1 = ks[d + 1]; extra = 1.0f;
    }
    rowp[cb + d] = (bf16)(v0 * r * s0 * extra);
    rowp[cb + d + 1] = (bf16)(v1 * r * s1 * extra);
  }
}

// ---------------- V transpose: qkv v-part -> Vt[b*4+kvh][d(128)][t(2048)] ---
__global__ __launch_bounds__(256) void k_vt(const bf16* __restrict__ qkv,
                                            bf16* __restrict__ Vt) {
  __shared__ bf16 t[64 * 65];
  int tid = threadIdx.x;
  int t0 = blockIdx.x * 64, d0 = blockIdx.y * 64;
  int bh = blockIdx.z;
  int b = bh >> 2, kvh = bh & 3;
  const bf16* src = qkv + (size_t)(b * 2048) * 3072 + 2560 + kvh * 128;
  bf16* dst = Vt + (size_t)bh * 128 * 2048;
#pragma unroll
  for (int i = 0; i < 16; ++i) {
    int f = i * 256 + tid;
    int tl = f >> 6, dl = f & 63;
    t[tl * 65 + dl] = src[(size_t)(t0 + tl) * 3072 + d0 + dl];
  }
  __syncthreads();
#pragma unroll
  for (int i = 0; i < 16; ++i) {
    int f = i * 256 + tid;
    int dl = f >> 6, tl = f & 63;
    dst[(size_t)(d0 + dl) * 2048 + t0 + tl] = t[tl * 65 + dl];
  }
}

__device__ inline unsigned pack2bf(float a, float b) {
  union { bf16 h[2]; unsigned u; } x;
  x.h[0] = (bf16)a;
  x.h[1] = (bf16)b;
  return x.u;
}

// ---------------- causal GQA flash attention (swapped QK, 32x32 MFMA) ------
// grid (qt=16 reversed, h=16, b=2), 4 waves x 32 q-rows (QBLK=128), KVBLK=64.
// K LDS: [chunk(16)][row(64)][8] double-buffered (32KB -> 4 blocks/CU).
// V read directly from L2-resident Vt[d][t] (no LDS staging, lesson m169).
__global__ __launch_bounds__(256, 4) void k_attn(const bf16* __restrict__ qkv,
                                                 const bf16* __restrict__ Vt,
                                                 bf16* __restrict__ y) {
  int qt = gridDim.x - 1 - blockIdx.x;  // heavy blocks dispatch first
  int h = blockIdx.y, b = blockIdx.z;
  int kvh = h >> 2;
  int tid = threadIdx.x;
  int wid = tid >> 6, lane = tid & 63;
  int qc = lane & 31, hi = lane >> 5;
  __shared__ alignas(16) bf16 Ks[2][16 * 64 * 8];  // 2 x 16KB
  const bf16* Qb = qkv + (size_t)(b * 2048) * 3072 + h * 128;
  const bf16* Kb = qkv + (size_t)(b * 2048) * 3072 + 2048 + kvh * 128;
  const bf16* Vb = Vt + (size_t)(b * 4 + kvh) * 128 * 2048;
  int qw0 = qt * 128 + wid * 32;  // wave's first q row
  int qg = qw0 + qc;              // this lane's q row
  // Q B-fragments: col=lane&31=q, k(d)=8*hi+j, 8 d-slices of 16
  bf16x8 qf[8];
#pragma unroll
  for (int s = 0; s < 8; ++s)
    qf[s] = *(const bf16x8*)&Qb[(size_t)qg * 3072 + s * 16 + hi * 8];
  f32x16 acc[4] = {};
  float mrun = -1e30f, lrun = 0.f;

  auto STAGE = [&](int buf, int kt2) {
    int s0 = kt2 * 64;
#pragma unroll
    for (int i = 0; i < 4; ++i) {  // K: slot = chunk*64+row
      int slot = i * 256 + tid;
      int ch = slot >> 6, row = slot & 63;
      LOAD_LDS16(Kb + (size_t)(s0 + row) * 3072 + ch * 8, &Ks[buf][slot * 8]);
    }
  };

  STAGE(0, 0);
  int cur = 0;
  int ktmax = 2 * qt + 1;
  for (int kt = 0; kt <= ktmax; ++kt) {
    int s0 = kt * 64;
    if (kt < ktmax) {
      STAGE(cur ^ 1, kt + 1);
      asm volatile("s_waitcnt vmcnt(4)" ::: "memory");
    } else {
      asm volatile("s_waitcnt vmcnt(0)" ::: "memory");
    }
    __builtin_amdgcn_s_barrier();
    __builtin_amdgcn_sched_barrier(0);
    if (s0 <= qw0 + 31) {  // wave has unmasked work in this tile
      // QK^T swapped: sc[n] = K_tile_n * Q^T -> D[k][q], col=lane&31=q
      f32x16 sc[2] = {};
#pragma unroll
      for (int s = 0; s < 8; ++s)
#pragma unroll
        for (int n = 0; n < 2; ++n) {
          bf16x8 kf =
              *(const bf16x8*)&Ks[cur][(((2 * s + hi) << 6) + n * 32 + qc) * 8];
          sc[n] =
              __builtin_amdgcn_mfma_f32_32x32x16_bf16(kf, qf[s], sc[n], 0, 0, 0);
        }
      if (s0 + 63 > qw0) {  // diagonal: causal mask
#pragma unroll
        for (int n = 0; n < 2; ++n)
#pragma unroll
          for (int r = 0; r < 16; ++r) {
            int kg = s0 + n * 32 + (r & 3) + 8 * (r >> 2) + 4 * hi;
            if (kg > qg) sc[n][r] = -1e30f;
          }
      }
      // per-lane max (lane owns its q-row) + pair reduce
      float pm = -1e30f;
#pragma unroll
      for (int n = 0; n < 2; ++n)
#pragma unroll
        for (int r = 0; r < 16; ++r) pm = fmaxf(pm, sc[n][r]);
      pm = fmaxf(pm, __shfl_xor(pm, 32));
      // deferred rescale (T13): only when max grew past threshold
      if (__any(pm > mrun + 11.0f)) {
        float mnew = fmaxf(mrun, pm);
        float scl = EXP2F(mrun - mnew);
        mrun = mnew;
        lrun *= scl;
        float sv[16];
#pragma unroll
        for (int r = 0; r < 16; ++r)
          sv[r] = __shfl(scl, (r & 3) + 8 * (r >> 2) + 4 * hi);
#pragma unroll
        for (int dt = 0; dt < 4; ++dt)
#pragma unroll
          for (int r = 0; r < 16; ++r) acc[dt][r] *= sv[r];
      }
      // P = exp2(sc - m); pack to bf16; assemble PV A-frags via permlane swap
      float rs = 0.f;
#pragma unroll
      for (int n = 0; n < 2; ++n) {
        unsigned pk[8];
#pragma unroll
        for (int mm = 0; mm < 8; ++mm) {
          float e0 = EXP2F(sc[n][2 * mm] - mrun);
          float e1 = EXP2F(sc[n][2 * mm + 1] - mrun);
          rs += e0 + e1;
          pk[mm] = pack2bf(e0, e1);
        }
#pragma unroll
        for (int l2 = 0; l2 < 2; ++l2) {
          unsigned a0 = pk[4 * l2 + 0], b0 = pk[4 * l2 + 2];
          unsigned a1 = pk[4 * l2 + 1], b1 = pk[4 * l2 + 3];
          asm volatile("v_permlane32_swap_b32 %0, %1" : "+v"(a0), "+v"(b0));
          asm volatile("v_permlane32_swap_b32 %0, %1" : "+v"(a1), "+v"(b1));
          u32x4 w = {a0, a1, b0, b1};
          bf16x8 pf = __builtin_bit_cast(bf16x8, w);
          int ksg = 2 * n + l2;
#pragma unroll
          for (int dt = 0; dt < 4; ++dt) {
            // V B-frag straight from L2: col=lane&31 -> d row of Vt,
            // k = 16*ksg + 8*hi + j contiguous in t.
            bf16x8 vf = *(const bf16x8*)&Vb[(size_t)(dt * 32 + qc) * 2048 + s0 +
                                            (2 * ksg + hi) * 8];
            acc[dt] =
                __builtin_amdgcn_mfma_f32_32x32x16_bf16(pf, vf, acc[dt], 0, 0, 0);
          }
        }
      }
      rs += __shfl_xor(rs, 32);
      lrun += rs;
    }
    __builtin_amdgcn_s_barrier();
    cur ^= 1;
  }
  // epilogue: normalize and store
  float rlv = 1.0f / lrun;
  float rcl[16];
#pragma unroll
  for (int r = 0; r < 16; ++r)
    rcl[r] = __shfl(rlv, (r & 3) + 8 * (r >> 2) + 4 * hi);
#pragma unroll
  for (int dt = 0; dt < 4; ++dt)
#pragma unroll
    for (int r = 0; r < 16; ++r) {
      int row = qw0 + (r & 3) + 8 * (r >> 2) + 4 * hi;
      float v = acc[dt][r] * rcl[r];
      y[(size_t)(b * 2048 + row) * 2048 + h * 128 + dt * 32 + qc] = (bf16)v;
    }
}

// ---------------- launcher ----------------
extern "C" void kernel_launch(void* const* d_in, const int* in_sizes, int n_in,
                              void* d_out, int out_size, void* d_ws,
                              size_t ws_size, hipStream_t stream) {
  const float* x = (const float*)d_in[0];
  const float* Wqkv = (const float*)d_in[1];
  const float* Wproj = (const float*)d_in[2];
  const float* qs = (const float*)d_in[3];
  const float* ks = (const float*)d_in[4];
  float* out = (float*)d_out;
  char* ws = (char*)d_ws;

  bf16* xb = (bf16*)(ws);
  bf16* Wqkvt = (bf16*)(ws + (size_t)(16u << 20));
  bf16* Wprojt = (bf16*)(ws + (size_t)(28u << 20));
  bf16* qkv = (bf16*)(ws + (size_t)(36u << 20));
  bf16* Vt = Wqkvt;  // reuse after Wqkvt consumed by G1
  bf16* y = xb;      // reuse after xb consumed by G1

  k_cvt_x<<<8192, 256, 0, stream>>>(x, xb, 8388608 / 4);
  k_transpose<<<dim3(3072 / 64, 2048 / 64), 256, 0, stream>>>(Wqkv, Wqkvt, 2048, 3072);
  k_transpose<<<dim3(2048 / 64, 2048 / 64), 256, 0, stream>>>(Wproj, Wprojt, 2048, 2048);
  k_gemm256<bf16, 256><<<dim3(16, 12), 512, 0, stream>>>(xb, Wqkvt, qkv, 4096, 3072, 2048);
  k_qknorm<<<4096, 256, 0, stream>>>(qkv, qs, ks);
  k_vt<<<dim3(32, 2, 8), 256, 0, stream>>>(qkv, Vt);
  k_attn<<<dim3(16, 16, 2), 256, 0, stream>>>(qkv, Vt, y);
  k_gemm256<float, 128><<<dim3(32, 8), 512, 0, stream>>>(y, Wprojt, out, 4096, 2048, 2048);
}

// Round 7
// 259.443 us; speedup vs baseline: 1.6472x; 1.6472x over previous
//
#include <hip/hip_runtime.h>

typedef __bf16 bf16;
typedef __bf16 bf16x8 __attribute__((ext_vector_type(8)));
typedef __bf16 bf16x4 __attribute__((ext_vector_type(4)));
typedef float f32x4 __attribute__((ext_vector_type(4)));
typedef float f32x16 __attribute__((ext_vector_type(16)));
typedef unsigned u32x4 __attribute__((ext_vector_type(4)));

#define EXP2F(x) __builtin_amdgcn_exp2f(x)

#define LOAD_LDS16(gp, lp)                                                     \
  __builtin_amdgcn_global_load_lds(                                            \
      (const __attribute__((address_space(1))) void*)(gp),                     \
      (__attribute__((address_space(3))) void*)(lp), 16, 0, 0)

// ---------------- f32 -> bf16 convert (x) ----------------
__global__ __launch_bounds__(256) void k_cvt_x(const float* __restrict__ in,
                                               bf16* __restrict__ out, int n4) {
  int i = blockIdx.x * 256 + threadIdx.x;
  if (i < n4) {
    float4 v = ((const float4*)in)[i];
    bf16x4 o = {(bf16)v.x, (bf16)v.y, (bf16)v.z, (bf16)v.w};
    ((bf16x4*)out)[i] = o;
  }
}

// ---------------- f32 [R][C] -> bf16 [C][R] transpose ----------------
__global__ __launch_bounds__(256) void k_transpose(const float* __restrict__ in,
                                                   bf16* __restrict__ out,
                                                   int R, int C) {
  __shared__ bf16 t[64 * 65];
  int tid = threadIdx.x;
  int c0 = blockIdx.x * 64, r0 = blockIdx.y * 64;
#pragma unroll
  for (int i = 0; i < 16; ++i) {
    int f = i * 256 + tid;
    int rl = f >> 6, cl = f & 63;
    t[rl * 65 + cl] = (bf16)in[(size_t)(r0 + rl) * C + c0 + cl];
  }
  __syncthreads();
#pragma unroll
  for (int i = 0; i < 16; ++i) {
    int f = i * 256 + tid;
    int cl = f >> 6, rl = f & 63;
    out[(size_t)(c0 + cl) * R + r0 + rl] = t[rl * 65 + cl];
  }
}

// ---- bf16 GEMM, BMx256 tile, 8-phase counted-vmcnt schedule (T3+T4+T5) ----
// De-pinned: no sched_barrier / blanket lgkmcnt — compiler emits fine-grained
// lgkm waits (m141 lesson). Correctness: vmcnt asm ("memory") + s_barriers
// certify staged buffers; ds_reads cannot cross the certifying asm.
template <typename OutT, int BM>
__global__ __launch_bounds__(512, 2) void k_gemm256(const bf16* __restrict__ A,
                                                    const bf16* __restrict__ Bt,
                                                    OutT* __restrict__ C,
                                                    int M, int N, int K) {
  constexpr int ASZ = 4 * BM * 8;   // elems per kh buffer
  constexpr int MREP = BM / 32;     // per-wave 16-row tiles (8 or 4)
  __shared__ alignas(16) bf16 As[2][2][ASZ];
  __shared__ alignas(16) bf16 Bs[2][2][4 * 256 * 8];
  int tid = threadIdx.x;
  int wid = tid >> 6, lane = tid & 63;
  int g = lane >> 4, lr = lane & 15;
  int wrow = (wid >> 2) * (BM / 2), wcol = (wid & 3) * 64;
  // XCD-aware bijective swizzle (nwg % 8 == 0 for both launches)
  int gx = gridDim.x;
  int flat = blockIdx.y * gx + blockIdx.x;
  int cpx = (gx * gridDim.y) >> 3;
  int f2 = (flat & 7) * cpx + (flat >> 3);
  int row0 = (f2 % gx) * BM, col0 = (f2 / gx) * 256;
  int NT = K >> 6;
  f32x4 acc[MREP][4] = {};

  auto stageA = [&](int buf, int kh, int kt) {
#pragma unroll
    for (int pass = 0; pass < BM / 128; ++pass) {
      int slot = pass * 512 + tid;
      int kseg, row;
      if constexpr (BM == 256) { kseg = slot >> 8; row = slot & 255; }
      else { kseg = slot >> 7; row = slot & 127; }
      LOAD_LDS16(A + (size_t)(row0 + row) * K + kt * 64 + kh * 32 + kseg * 8,
                 &As[buf][kh][slot * 8]);
    }
  };
  auto stageB = [&](int buf, int kh, int kt) {
#pragma unroll
    for (int pass = 0; pass < 2; ++pass) {
      int slot = pass * 512 + tid;
      int kseg = slot >> 8, row = slot & 255;
      LOAD_LDS16(Bt + (size_t)(col0 + row) * K + kt * 64 + kh * 32 + kseg * 8,
                 &Bs[buf][kh][slot * 8]);
    }
  };
  auto dsA = [&](int buf, int s, int mq, bf16x8* af) {
#pragma unroll
    for (int i = 0; i < 4; ++i)
      af[i] = *(const bf16x8*)&As[buf][s]
                  [(g * BM + wrow + (mq * 4 + i) * 16 + lr) * 8];
  };
  auto dsB = [&](int buf, int s, bf16x8* bfr) {
#pragma unroll
    for (int i = 0; i < 4; ++i)
      bfr[i] = *(const bf16x8*)&Bs[buf][s][((g << 8) + wcol + i * 16 + lr) * 8];
  };
  auto mfma16 = [&](int mq, bf16x8* af, bf16x8* bfr) {
    __builtin_amdgcn_s_setprio(1);
#pragma unroll
    for (int i = 0; i < 4; ++i)
#pragma unroll
      for (int n = 0; n < 4; ++n)
        acc[mq * 4 + i][n] = __builtin_amdgcn_mfma_f32_16x16x32_bf16(
            af[i], bfr[n], acc[mq * 4 + i][n], 0, 0, 0);
    __builtin_amdgcn_s_setprio(0);
  };

  // prologue: tile 0 fully; certify kh0(0)
  stageA(0, 0, 0);
  stageB(0, 0, 0);
  stageA(0, 1, 0);
  stageB(0, 1, 0);
  if constexpr (BM == 256)
    asm volatile("s_waitcnt vmcnt(4)" ::: "memory");
  else
    asm volatile("s_waitcnt vmcnt(3)" ::: "memory");
  __builtin_amdgcn_s_barrier();

  for (int T = 0; T < NT; ++T) {
    int buf = T & 1, nbuf = buf ^ 1;
    bool more = (T + 1 < NT);
    bf16x8 af[4], bfr[4];
    if constexpr (BM == 256) {
      // ---- p0: kh0, mq0 ----
      dsA(buf, 0, 0, af);
      dsB(buf, 0, bfr);
      if (more) stageA(nbuf, 0, T + 1);
      __builtin_amdgcn_s_barrier();
      mfma16(0, af, bfr);
      __builtin_amdgcn_s_barrier();
      // ---- p1: kh0, mq1 ----
      dsA(buf, 0, 1, af);
      if (more) {
        stageB(nbuf, 0, T + 1);
        asm volatile("s_waitcnt vmcnt(4)" ::: "memory");  // kh1(T) landed
      } else {
        asm volatile("s_waitcnt vmcnt(0)" ::: "memory");
      }
      __builtin_amdgcn_s_barrier();
      mfma16(1, af, bfr);
      __builtin_amdgcn_s_barrier();
      // ---- p2: kh1, mq0 ----
      dsA(buf, 1, 0, af);
      dsB(buf, 1, bfr);
      if (more) stageA(nbuf, 1, T + 1);
      __builtin_amdgcn_s_barrier();
      mfma16(0, af, bfr);
      __builtin_amdgcn_s_barrier();
      // ---- p3: kh1, mq1 ----
      dsA(buf, 1, 1, af);
      if (more) {
        stageB(nbuf, 1, T + 1);
        asm volatile("s_waitcnt vmcnt(4)" ::: "memory");  // kh0(T+1) landed
      }
      __builtin_amdgcn_s_barrier();
      mfma16(1, af, bfr);
      __builtin_amdgcn_s_barrier();
    } else {
      // ---- p0: kh0 ----
      dsA(buf, 0, 0, af);
      dsB(buf, 0, bfr);
      if (more) {
        stageA(nbuf, 0, T + 1);
        stageB(nbuf, 0, T + 1);
        asm volatile("s_waitcnt vmcnt(3)" ::: "memory");  // kh1(T) landed
      } else {
        asm volatile("s_waitcnt vmcnt(0)" ::: "memory");
      }
      __builtin_amdgcn_s_barrier();
      mfma16(0, af, bfr);
      __builtin_amdgcn_s_barrier();
      // ---- p1: kh1 ----
      dsA(buf, 1, 0, af);
      dsB(buf, 1, bfr);
      if (more) {
        stageA(nbuf, 1, T + 1);
        stageB(nbuf, 1, T + 1);
        asm volatile("s_waitcnt vmcnt(3)" ::: "memory");  // kh0(T+1) landed
      }
      __builtin_amdgcn_s_barrier();
      mfma16(0, af, bfr);
      __builtin_amdgcn_s_barrier();
    }
  }

#pragma unroll
  for (int mi = 0; mi < MREP; ++mi)
#pragma unroll
    for (int ni = 0; ni < 4; ++ni) {
      int rb = row0 + wrow + mi * 16 + g * 4;
      int cc = col0 + wcol + ni * 16 + lr;
#pragma unroll
      for (int r = 0; r < 4; ++r) {
        float v = acc[mi][ni][r];
        C[(size_t)(rb + r) * N + cc] = (OutT)v;
      }
    }
}

// ---------------- QK RMS-norm (in place on bf16 qkv) ----------------
// Q gets 1/sqrt(128) * log2(e) folded in (softmax done in exp2 domain).
__global__ __launch_bounds__(256) void k_qknorm(bf16* __restrict__ qkv,
                                                const float* __restrict__ qs,
                                                const float* __restrict__ ks) {
  int tok = blockIdx.x;
  int wid = threadIdx.x >> 6, lane = threadIdx.x & 63;
  int d = lane * 2;
  bf16* rowp = qkv + (size_t)tok * 3072;
#pragma unroll
  for (int i = 0; i < 5; ++i) {
    int cb = (i < 4) ? (wid + i * 4) * 128 : 2048 + wid * 128;
    float v0 = (float)rowp[cb + d], v1 = (float)rowp[cb + d + 1];
    float ss = v0 * v0 + v1 * v1;
#pragma unroll
    for (int off = 1; off < 64; off <<= 1) ss += __shfl_xor(ss, off);
    float r = rsqrtf(ss * (1.0f / 128.0f) + 1e-6f);
    float s0, s1, extra;
    if (i < 4) {
      s0 = qs[d]; s1 = qs[d + 1];
      extra = 0.08838834764831845f * 1.4426950408889634f;  // rsqrt(d)*log2(e)
    } else {
      s0 = ks[d]; s1 = ks[d + 1]; extra = 1.0f;
    }
    rowp[cb + d] = (bf16)(v0 * r * s0 * extra);
    rowp[cb + d + 1] = (bf16)(v1 * r * s1 * extra);
  }
}

// ---------------- V transpose: qkv v-part -> Vt[b*4+kvh][d(128)][t(2048)] ---
__global__ __launch_bounds__(256) void k_vt(const bf16* __restrict__ qkv,
                                            bf16* __restrict__ Vt) {
  __shared__ bf16 t[64 * 65];
  int tid = threadIdx.x;
  int t0 = blockIdx.x * 64, d0 = blockIdx.y * 64;
  int bh = blockIdx.z;
  int b = bh >> 2, kvh = bh & 3;
  const bf16* src = qkv + (size_t)(b * 2048) * 3072 + 2560 + kvh * 128;
  bf16* dst = Vt + (size_t)bh * 128 * 2048;
#pragma unroll
  for (int i = 0; i < 16; ++i) {
    int f = i * 256 + tid;
    int tl = f >> 6, dl = f & 63;
    t[tl * 65 + dl] = src[(size_t)(t0 + tl) * 3072 + d0 + dl];
  }
  __syncthreads();
#pragma unroll
  for (int i = 0; i < 16; ++i) {
    int f = i * 256 + tid;
    int dl = f >> 6, tl = f & 63;
    dst[(size_t)(d0 + dl) * 2048 + t0 + tl] = t[tl * 65 + dl];
  }
}

__device__ inline unsigned pack2bf(float a, float b) {
  union { bf16 h[2]; unsigned u; } x;
  x.h[0] = (bf16)a;
  x.h[1] = (bf16)b;
  return x.u;
}

// ---------------- causal GQA flash attention (swapped QK, 32x32 MFMA) ------
// Round-5 validated version (LDS-staged K AND V, dbuf, vmcnt(8)) + XCD-local
// grid decode: flat 512 blocks; xcd=flat&7 gets heads {xcd, xcd+8} only.
__global__ __launch_bounds__(256, 2) void k_attn(const bf16* __restrict__ qkv,
                                                 const bf16* __restrict__ Vt,
                                                 bf16* __restrict__ y) {
  int flat = blockIdx.x;
  int xcd = flat & 7, iw = flat >> 3;
  int h = xcd + 8 * (iw & 1);
  int rem = iw >> 1;           // 0..31
  int b = rem >> 4;
  int qt = 15 - (rem & 15);    // heavy blocks dispatch first
  int kvh = h >> 2;
  int tid = threadIdx.x;
  int wid = tid >> 6, lane = tid & 63;
  int qc = lane & 31, hi = lane >> 5;
  __shared__ alignas(16) bf16 Ks[2][16 * 64 * 8];  // 2 x 16KB
  __shared__ alignas(16) bf16 Vs[2][128 * 64];     // 2 x 16KB
  const bf16* Qb = qkv + (size_t)(b * 2048) * 3072 + h * 128;
  const bf16* Kb = qkv + (size_t)(b * 2048) * 3072 + 2048 + kvh * 128;
  const bf16* Vb = Vt + (size_t)(b * 4 + kvh) * 128 * 2048;
  int qw0 = qt * 128 + wid * 32;  // wave's first q row
  int qg = qw0 + qc;              // this lane's q row
  // Q B-fragments: col=lane&31=q, k(d)=8*hi+j, 8 d-slices of 16
  bf16x8 qf[8];
#pragma unroll
  for (int s = 0; s < 8; ++s)
    qf[s] = *(const bf16x8*)&Qb[(size_t)qg * 3072 + s * 16 + hi * 8];
  f32x16 acc[4] = {};
  float mrun = -1e30f, lrun = 0.f;

  auto STAGE = [&](int buf, int kt2) {
    int s0 = kt2 * 64;
#pragma unroll
    for (int i = 0; i < 4; ++i) {  // K: slot = chunk*64+row
      int slot = i * 256 + tid;
      int ch = slot >> 6, row = slot & 63;
      LOAD_LDS16(Kb + (size_t)(s0 + row) * 3072 + ch * 8, &Ks[buf][slot * 8]);
    }
#pragma unroll
    for (int i = 0; i < 4; ++i) {  // V: slot = d*8+c, source pre-swizzled
      int slot = i * 256 + tid;
      int d = slot >> 3, c = slot & 7;
      LOAD_LDS16(Vb + (size_t)d * 2048 + s0 + ((c ^ (d & 7)) * 8),
                 &Vs[buf][slot * 8]);
    }
  };

  STAGE(0, 0);
  int cur = 0;
  int ktmax = 2 * qt + 1;
  for (int kt = 0; kt <= ktmax; ++kt) {
    int s0 = kt * 64;
    if (kt < ktmax) {
      STAGE(cur ^ 1, kt + 1);
      asm volatile("s_waitcnt vmcnt(8)" ::: "memory");
    } else {
      asm volatile("s_waitcnt vmcnt(0)" ::: "memory");
    }
    __builtin_amdgcn_s_barrier();
    __builtin_amdgcn_sched_barrier(0);
    if (s0 <= qw0 + 31) {  // wave has unmasked work in this tile
      // QK^T swapped: sc[n] = K_tile_n * Q^T -> D[k][q], col=lane&31=q
      f32x16 sc[2] = {};
#pragma unroll
      for (int s = 0; s < 8; ++s)
#pragma unroll
        for (int n = 0; n < 2; ++n) {
          bf16x8 kf =
              *(const bf16x8*)&Ks[cur][(((2 * s + hi) << 6) + n * 32 + qc) * 8];
          sc[n] =
              __builtin_amdgcn_mfma_f32_32x32x16_bf16(kf, qf[s], sc[n], 0, 0, 0);
        }
      if (s0 + 63 > qw0) {  // diagonal: causal mask
#pragma unroll
        for (int n = 0; n < 2; ++n)
#pragma unroll
          for (int r = 0; r < 16; ++r) {
            int kg = s0 + n * 32 + (r & 3) + 8 * (r >> 2) + 4 * hi;
            if (kg > qg) sc[n][r] = -1e30f;
          }
      }
      // per-lane max (lane owns its q-row) + pair reduce
      float pm = -1e30f;
#pragma unroll
      for (int n = 0; n < 2; ++n)
#pragma unroll
        for (int r = 0; r < 16; ++r) pm = fmaxf(pm, sc[n][r]);
      pm = fmaxf(pm, __shfl_xor(pm, 32));
      // deferred rescale (T13): only when max grew past threshold
      if (__any(pm > mrun + 11.0f)) {
        float mnew = fmaxf(mrun, pm);
        float scl = EXP2F(mrun - mnew);
        mrun = mnew;
        lrun *= scl;
        float sv[16];
#pragma unroll
        for (int r = 0; r < 16; ++r)
          sv[r] = __shfl(scl, (r & 3) + 8 * (r >> 2) + 4 * hi);
#pragma unroll
        for (int dt = 0; dt < 4; ++dt)
#pragma unroll
          for (int r = 0; r < 16; ++r) acc[dt][r] *= sv[r];
      }
      // P = exp2(sc - m); pack to bf16; assemble PV A-frags via permlane swap
      float rs = 0.f;
#pragma unroll
      for (int n = 0; n < 2; ++n) {
        unsigned pk[8];
#pragma unroll
        for (int mm = 0; mm < 8; ++mm) {
          float e0 = EXP2F(sc[n][2 * mm] - mrun);
          float e1 = EXP2F(sc[n][2 * mm + 1] - mrun);
          rs += e0 + e1;
          pk[mm] = pack2bf(e0, e1);
        }
#pragma unroll
        for (int l2 = 0; l2 < 2; ++l2) {
          unsigned a0 = pk[4 * l2 + 0], b0 = pk[4 * l2 + 2];
          unsigned a1 = pk[4 * l2 + 1], b1 = pk[4 * l2 + 3];
          asm volatile("v_permlane32_swap_b32 %0, %1" : "+v"(a0), "+v"(b0));
          asm volatile("v_permlane32_swap_b32 %0, %1" : "+v"(a1), "+v"(b1));
          u32x4 w = {a0, a1, b0, b1};
          bf16x8 pf = __builtin_bit_cast(bf16x8, w);
          int ksg = 2 * n + l2;
#pragma unroll
          for (int dt = 0; dt < 4; ++dt) {
            int drow = dt * 32 + qc;
            bf16x8 vf = *(const bf16x8*)&Vs[cur][(drow * 8 +
                                                  ((2 * ksg + hi) ^ (qc & 7))) *
                                                 8];
            acc[dt] =
                __builtin_amdgcn_mfma_f32_32x32x16_bf16(pf, vf, acc[dt], 0, 0, 0);
          }
        }
      }
      rs += __shfl_xor(rs, 32);
      lrun += rs;
    }
    __builtin_amdgcn_s_barrier();
    cur ^= 1;
  }
  // epilogue: normalize and store
  float rlv = 1.0f / lrun;
  float rcl[16];
#pragma unroll
  for (int r = 0; r < 16; ++r)
    rcl[r] = __shfl(rlv, (r & 3) + 8 * (r >> 2) + 4 * hi);
#pragma unroll
  for (int dt = 0; dt < 4; ++dt)
#pragma unroll
    for (int r = 0; r < 16; ++r) {
      int row = qw0 + (r & 3) + 8 * (r >> 2) + 4 * hi;
      float v = acc[dt][r] * rcl[r];
      y[(size_t)(b * 2048 + row) * 2048 + h * 128 + dt * 32 + qc] = (bf16)v;
    }
}

// ---------------- launcher ----------------
extern "C" void kernel_launch(void* const* d_in, const int* in_sizes, int n_in,
                              void* d_out, int out_size, void* d_ws,
                              size_t ws_size, hipStream_t stream) {
  const float* x = (const float*)d_in[0];
  const float* Wqkv = (const float*)d_in[1];
  const float* Wproj = (const float*)d_in[2];
  const float* qs = (const float*)d_in[3];
  const float* ks = (const float*)d_in[4];
  float* out = (float*)d_out;
  char* ws = (char*)d_ws;

  bf16* xb = (bf16*)(ws);
  bf16* Wqkvt = (bf16*)(ws + (size_t)(16u << 20));
  bf16* Wprojt = (bf16*)(ws + (size_t)(28u << 20));
  bf16* qkv = (bf16*)(ws + (size_t)(36u << 20));
  bf16* Vt = Wqkvt;  // reuse after Wqkvt consumed by G1
  bf16* y = xb;      // reuse after xb consumed by G1

  k_cvt_x<<<8192, 256, 0, stream>>>(x, xb, 8388608 / 4);
  k_transpose<<<dim3(3072 / 64, 2048 / 64), 256, 0, stream>>>(Wqkv, Wqkvt, 2048, 3072);
  k_transpose<<<dim3(2048 / 64, 2048 / 64), 256, 0, stream>>>(Wproj, Wprojt, 2048, 2048);
  k_gemm256<bf16, 256><<<dim3(16, 12), 512, 0, stream>>>(xb, Wqkvt, qkv, 4096, 3072, 2048);
  k_qknorm<<<4096, 256, 0, stream>>>(qkv, qs, ks);
  k_vt<<<dim3(32, 2, 8), 256, 0, stream>>>(qkv, Vt);
  k_attn<<<dim3(512, 1, 1), 256, 0, stream>>>(qkv, Vt, y);
  k_gemm256<float, 128><<<dim3(32, 8), 512, 0, stream>>>(y, Wprojt, out, 4096, 2048, 2048);
}